// Round 13
// baseline (61.162 us; speedup 1.0000x reference)
//
#include <hip/hip_runtime.h>
#include <hip/hip_bf16.h>
#include <math.h>

#define B_ 4
#define C_ 128
#define H_ 256
#define W_ 256
#define NK 2048
#define NP 8
#define HW_ (H_*W_)
#define MAXOFF 64.0f
#define NROWS (B_*NK)          // 8192

typedef short s16x8 __attribute__((ext_vector_type(8)));
typedef float f32x4 __attribute__((ext_vector_type(4)));

#define SELU_SC 1.0507009873554805f
#define SELU_AL 1.6732632423543772f

#define N_W1F (36*64*8)     // 18432
#define N_SFB (8*4*64*8)    // 16384
#define N_AGG (8*8*4*64*8)  // 131072
#define NPREP (N_W1F + N_SFB + N_AGG)   // 165888
#define NT_BLK (B_*HW_/64)               // 4096 transpose tiles
#define NP_BLK 81
#define LSTR 136

__device__ inline float bf2f(short b) {
    union { unsigned int u; float f; } cv;
    cv.u = ((unsigned int)(unsigned short)b) << 16;
    return cv.f;
}
__device__ inline short f2bf_s(float f) {
    __hip_bfloat16 h = __float2bfloat16(f);
    return *(short*)&h;
}

// ---- K0: transpose x (B,C,H,W) fp32 -> xt (B,H,W,C) bf16  (+ fused preps) --
__global__ __launch_bounds__(256) void k_transpose_prep(const float* __restrict__ x,
        __hip_bfloat16* __restrict__ xt,
        const float* __restrict__ W1, const float* __restrict__ sf_w,
        const float* __restrict__ agg_w,
        __hip_bfloat16* __restrict__ w1f, __hip_bfloat16* __restrict__ sfb,
        __hip_bfloat16* __restrict__ aggb) {
    __shared__ __align__(16) __hip_bfloat16 lt[64*LSTR];
    int bid = blockIdx.x;
    int t = threadIdx.x;
    if (bid >= NT_BLK) {
        int base = ((bid - NT_BLK)*256 + t)*8;
        #pragma unroll
        for (int j = 0; j < 8; ++j) {
            int u0 = base + j;
            if (u0 < N_W1F) {
                int e = u0 & 7, l = (u0 >> 3) & 63, ks = u0 >> 9;
                int o = l & 15, c = (ks & 3)*32 + ((l >> 4) << 3) + e, ab = ks >> 2;
                w1f[u0] = __float2bfloat16(W1[o*1152 + c*9 + ab]);
            } else if (u0 < N_W1F + N_SFB) {
                int u = u0 - N_W1F;
                int e = u & 7, l = (u >> 3) & 63, ks = (u >> 9) & 3, jj = u >> 11;
                sfb[u] = __float2bfloat16(sf_w[(jj*16 + (l & 15))*128 + ks*32 + ((l >> 4) << 3) + e]);
            } else if (u0 < NPREP) {
                int u = u0 - N_W1F - N_SFB;
                int e = u & 7, l = (u >> 3) & 63, ks = (u >> 9) & 3, p = (u >> 11) & 7, jd = u >> 14;
                aggb[u] = __float2bfloat16(agg_w[((size_t)p*128 + ks*32 + ((l >> 4) << 3) + e)*128 + jd*16 + (l & 15)]);
            }
        }
        return;
    }
    int i = bid >> 10;
    int hw0 = (bid & 1023) * 64;
    const float* src = x + (size_t)i*C_*HW_ + hw0;
    #pragma unroll
    for (int k = 0; k < 8; ++k) {
        int f = t + k*256;
        int c = f >> 4, hq = f & 15;
        float4 v = *(const float4*)(src + (size_t)c*HW_ + hq*4);
        int hw = hq*4;
        lt[(hw+0)*LSTR + c] = __float2bfloat16(v.x);
        lt[(hw+1)*LSTR + c] = __float2bfloat16(v.y);
        lt[(hw+2)*LSTR + c] = __float2bfloat16(v.z);
        lt[(hw+3)*LSTR + c] = __float2bfloat16(v.w);
    }
    __syncthreads();
    __hip_bfloat16* dst = xt + ((size_t)i*HW_ + hw0)*C_;
    #pragma unroll
    for (int k = 0; k < 4; ++k) {
        int e = t + k*256;
        int hw = e >> 4, c0 = (e & 15)*8;
        *(s16x8*)(dst + (size_t)hw*C_ + c0) = *(const s16x8*)&lt[hw*LSTR + c0];
    }
}

// ------------- K1: fused pipeline, 512 thr / 8 waves, 16 kp/block ----------
// Phase B+C merged: each lane gathers its own MFMA A-fragment directly
// (kp = r16, p = w, channels ks*32 + q*8) - no featL LDS round-trip.
#define HSTR 136
#define RSTR 132
#define SMEM_BYTES 34816   // max(Cp+hLr 9792, Hl 8*4352=34816, red 33792)
__global__ __launch_bounds__(512, 4) void k_fused(
        const __hip_bfloat16* __restrict__ xtb, const float* __restrict__ kpts,
        const __hip_bfloat16* __restrict__ w1f, const float* __restrict__ b1,
        const float* __restrict__ W2, const float* __restrict__ b2,
        const __hip_bfloat16* __restrict__ sfb, const __hip_bfloat16* __restrict__ aggb,
        float* __restrict__ out_off, float* __restrict__ descs) {
    __shared__ __align__(16) char smem[SMEM_BYTES];
    __shared__ float W2s[16][16];
    __shared__ float posL[16][8][2];
    __shared__ float kwx[16], kwy[16];
    __shared__ int   kcx[16], kcy[16];

    int t = threadIdx.x;
    int blk = blockIdx.x;
    int i = blk >> 7;                  // 128 blocks per image
    int w = t >> 6, l = t & 63;
    int r16 = l & 15, q = l >> 4;
    int kp0 = blk * 16;

    if (t < 16) {
        int gk = kp0 + t;
        float kx = kpts[(size_t)gk*2], ky = kpts[(size_t)gk*2 + 1];
        float wx = (kx*0.5f + 0.5f) * (float)(W_-1);
        float wy = (ky*0.5f + 0.5f) * (float)(H_-1);
        int cx = (int)wx - 1; cx = min(max(cx, 0), W_-1-3);
        int cy = (int)wy - 1; cy = min(max(cy, 0), H_-1-3);
        kwx[t] = wx; kwy[t] = wy; kcx[t] = cx; kcy[t] = cy;
    }
    if (t < 256) W2s[t >> 4][t & 15] = W2[t];
    __syncthreads();

    // ---- Phase A: patch conv MFMA; 36 k-steps over 8 waves (5,5,5,5,4,4,4,4)
    float* Cp  = (float*)smem;            // [8][16][17] = 8704 B
    float* hLr = (float*)(smem + 8704);   // [16][17]    = 1088 B
    {
        const char* pb = (const char*)(xtb +
            ((size_t)(i*H_ + kcy[r16])*W_ + kcx[r16])*C_);
        f32x4 acc = {0.f, 0.f, 0.f, 0.f};
        int nst  = (w < 4) ? 5 : 4;
        int kbase = (w < 4) ? w*5 : 20 + (w-4)*4;
        for (int s = 0; s < nst; ++s) {
            int ks = kbase + s;
            int ab = ks >> 2;
            int a = ab/3, b = ab - (ab/3)*3;
            int off = ((a*W_ + b)*C_ + (ks & 3)*32 + q*8) * 2;
            s16x8 af = *(const s16x8*)(pb + off);
            s16x8 bf = *(const s16x8*)((const short*)w1f + ((size_t)ks*64 + l)*8);
            acc = __builtin_amdgcn_mfma_f32_16x16x32_bf16(af, bf, acc, 0, 0, 0);
        }
        #pragma unroll
        for (int r = 0; r < 4; ++r)
            Cp[(w*16 + q*4 + r)*17 + r16] = acc[r];
    }
    __syncthreads();
    // ---- MLP + pos (threads 0..255) ----
    if (t < 256) {
        int kp = t >> 4, o = t & 15;
        float sum = 0.f;
        #pragma unroll
        for (int ww = 0; ww < 8; ++ww)
            sum += Cp[(ww*16 + kp)*17 + o];
        hLr[kp*17 + o] = fmaxf(sum + b1[o], 0.f);
    }
    __syncthreads();
    if (t < 256) {
        int kp = t >> 4, o = t & 15;
        float acc2 = b2[o];
        #pragma unroll
        for (int oo = 0; oo < 16; ++oo)
            acc2 += hLr[kp*17 + oo] * W2s[o][oo];
        acc2 = fminf(fmaxf(acc2, -MAXOFF), MAXOFF);
        int d = o >> 3, p = o & 7;
        int gk = kp0 + kp;
        out_off[((size_t)gk*NP + p)*2 + d] = acc2;
        posL[kp][p][d] = (d ? kwy[kp] : kwx[kp]) + acc2;
    }
    __syncthreads();   // Cp/hLr dead after this; smem reused as Hl below

    // ---- Phase B+C: direct gather into A-fragments (kp=r16, p=w) ----
    int p = w;
    s16x8 af[4];
    {
        float px = posL[r16][p][0], py = posL[r16][p][1];
        float x0f = floorf(px), y0f = floorf(py);
        int x0 = (int)x0f, y0 = (int)y0f;
        float wx1 = px - x0f, wy1 = py - y0f;
        float wx0 = 1.f - wx1, wy0 = 1.f - wy1;
        const __hip_bfloat16* tp[4];
        float wv[4];
        #pragma unroll
        for (int tap = 0; tap < 4; ++tap) {
            int xi = x0 + (tap & 1);
            int yi = y0 + (tap >> 1);
            float wgt = ((tap & 1) ? wx1 : wx0) * ((tap >> 1) ? wy1 : wy0);
            bool valid = (xi >= 0) & (xi < W_) & (yi >= 0) & (yi < H_);
            int xc = min(max(xi, 0), W_-1);
            int yc = min(max(yi, 0), H_-1);
            wv[tap] = valid ? wgt : 0.f;
            tp[tap] = xtb + ((size_t)(i*H_ + yc)*W_ + xc)*C_ + q*8;
        }
        #pragma unroll
        for (int ks = 0; ks < 4; ++ks) {
            float a0=0.f,a1=0.f,a2=0.f,a3=0.f,a4=0.f,a5=0.f,a6=0.f,a7=0.f;
            #pragma unroll
            for (int tap = 0; tap < 4; ++tap) {
                s16x8 v = *(const s16x8*)(tp[tap] + ks*32);
                float wt = wv[tap];
                a0 += wt * bf2f(v[0]);
                a1 += wt * bf2f(v[1]);
                a2 += wt * bf2f(v[2]);
                a3 += wt * bf2f(v[3]);
                a4 += wt * bf2f(v[4]);
                a5 += wt * bf2f(v[5]);
                a6 += wt * bf2f(v[6]);
                a7 += wt * bf2f(v[7]);
            }
            af[ks][0] = f2bf_s(a0); af[ks][1] = f2bf_s(a1);
            af[ks][2] = f2bf_s(a2); af[ks][3] = f2bf_s(a3);
            af[ks][4] = f2bf_s(a4); af[ks][5] = f2bf_s(a5);
            af[ks][6] = f2bf_s(a6); af[ks][7] = f2bf_s(a7);
        }
    }

    __hip_bfloat16* Hl = (__hip_bfloat16*)(smem + (size_t)w*4352);  // [16][HSTR]
    f32x4 dacc[8];
    #pragma unroll
    for (int jd = 0; jd < 8; ++jd) dacc[jd] = (f32x4){0.f,0.f,0.f,0.f};
    #pragma unroll
    for (int j = 0; j < 8; ++j) {
        f32x4 acc = (f32x4){0.f,0.f,0.f,0.f};
        const short* sb = (const short*)sfb + ((j*4)*64 + l)*8;
        #pragma unroll
        for (int ks = 0; ks < 4; ++ks)
            acc = __builtin_amdgcn_mfma_f32_16x16x32_bf16(af[ks], *(const s16x8*)(sb + ks*512), acc, 0, 0, 0);
        #pragma unroll
        for (int r = 0; r < 4; ++r) {
            float v = acc[r];
            v = v > 0.f ? SELU_SC*v : SELU_SC*SELU_AL*(__expf(v) - 1.0f);
            Hl[(q*4 + r)*HSTR + j*16 + r16] = __float2bfloat16(v);
        }
    }
    s16x8 ah[4];
    #pragma unroll
    for (int ks = 0; ks < 4; ++ks)
        ah[ks] = *(const s16x8*)(Hl + r16*HSTR + ks*32 + q*8);
    #pragma unroll
    for (int jd = 0; jd < 8; ++jd) {
        const short* ab = (const short*)aggb + (((jd*8 + p)*4)*64 + l)*8;
        #pragma unroll
        for (int ks = 0; ks < 4; ++ks)
            dacc[jd] = __builtin_amdgcn_mfma_f32_16x16x32_bf16(ah[ks], *(const s16x8*)(ab + ks*512), dacc[jd], 0, 0, 0);
    }
    __syncthreads();   // all Hl reads done; smem becomes red [4][16][RSTR]

    // ---- two-round reduction over 8 waves ----
    float* red = (float*)smem;
    if (w < 4) {
        #pragma unroll
        for (int jd = 0; jd < 8; ++jd)
            #pragma unroll
            for (int r = 0; r < 4; ++r)
                red[((size_t)w*16 + q*4 + r)*RSTR + jd*16 + r16] = dacc[jd][r];
    }
    __syncthreads();
    if (w >= 4) {
        #pragma unroll
        for (int jd = 0; jd < 8; ++jd)
            #pragma unroll
            for (int r = 0; r < 4; ++r) {
                size_t idx = ((size_t)(w-4)*16 + q*4 + r)*RSTR + jd*16 + r16;
                red[idx] += dacc[jd][r];
            }
    }
    __syncthreads();

    // ---- fused L2-normalize + store (16 rows x 128 cols over 512 thr) ----
    {
        int row = t >> 5, c5 = t & 31;
        float v[4];
        float ss = 0.f;
        #pragma unroll
        for (int k = 0; k < 4; ++k) {
            int col = c5 + 32*k;
            float s = red[(0*16 + row)*RSTR + col] + red[(1*16 + row)*RSTR + col]
                    + red[(2*16 + row)*RSTR + col] + red[(3*16 + row)*RSTR + col];
            v[k] = s; ss += s*s;
        }
        ss += __shfl_xor(ss, 1);
        ss += __shfl_xor(ss, 2);
        ss += __shfl_xor(ss, 4);
        ss += __shfl_xor(ss, 8);
        ss += __shfl_xor(ss, 16);
        float sc = fmaxf(sqrtf(ss), 1e-12f);
        #pragma unroll
        for (int k = 0; k < 4; ++k)
            descs[(size_t)(kp0 + row)*C_ + c5 + 32*k] = v[k] / sc;
    }
}

// ---------------- fallback path (no workspace): fp32 direct -----------------
__global__ __launch_bounds__(64) void k_offsets_f32(const float* __restrict__ xin,
        const float* __restrict__ kpts, const float* __restrict__ W1,
        const float* __restrict__ b1, const float* __restrict__ W2,
        const float* __restrict__ b2, float* __restrict__ out_off,
        float* __restrict__ pos) {
    __shared__ float pL[1152];
    __shared__ float hL2[16];
    __shared__ float oL[16];
    int bid = blockIdx.x;
    int i = bid >> 11;
    int t = threadIdx.x;
    float kx = kpts[(size_t)bid*2 + 0];
    float ky = kpts[(size_t)bid*2 + 1];
    float kwhx = (kx*0.5f + 0.5f) * (float)(W_-1);
    float kwhy = (ky*0.5f + 0.5f) * (float)(H_-1);
    int cx = (int)kwhx - 1; cx = cx < 0 ? 0 : (cx > 252 ? 252 : cx);
    int cy = (int)kwhy - 1; cy = cy < 0 ? 0 : (cy > 252 ? 252 : cy);
    for (int e = t; e < 1152; e += 64) {
        int a = e/384; int r = e - a*384; int b = r >> 7; int c = r & 127;
        pL[e] = xin[(((size_t)(i*C_ + c))*H_ + cy + a)*W_ + cx + b];
    }
    __syncthreads();
    int o = t & 15;
    int chunk = t >> 4;
    float partial = 0.f;
    const float* w1r = W1 + o*1152;
    for (int c = chunk*32; c < chunk*32 + 32; ++c) {
        #pragma unroll
        for (int ab = 0; ab < 9; ++ab) {
            const int a = ab/3, b = ab - (ab/3)*3;
            partial += w1r[c*9 + ab] * pL[a*384 + b*128 + c];
        }
    }
    partial += __shfl_xor(partial, 16);
    partial += __shfl_xor(partial, 32);
    float h1 = fmaxf(partial + b1[o], 0.f);
    if (t < 16) hL2[t] = h1;
    __syncthreads();
    if (t < 16) {
        float acc = b2[t];
        const float* w2r = W2 + t*16;
        #pragma unroll
        for (int oo = 0; oo < 16; ++oo) acc += w2r[oo]*hL2[oo];
        acc = fminf(fmaxf(acc, -MAXOFF), MAXOFF);
        oL[t] = acc;
    }
    __syncthreads();
    if (t < 8) {
        float ox = oL[t], oy = oL[8 + t];
        size_t base = ((size_t)bid*NP + t)*2;
        out_off[base]   = ox;
        out_off[base+1] = oy;
        pos[base]   = kwhx + ox;
        pos[base+1] = kwhy + oy;
    }
}

__global__ __launch_bounds__(128) void k_sample_f32(const float* __restrict__ xin,
        const float* __restrict__ pos, const float* __restrict__ sf_w,
        const float* __restrict__ agg_w, float* __restrict__ dst) {
    __shared__ __align__(16) float featL[NP*C_];
    __shared__ float pp[16];
    int bid = blockIdx.x;
    int i = bid >> 11;
    int c = threadIdx.x;
    if (c < 16) pp[c] = pos[(size_t)bid*16 + c];
    __syncthreads();
    #pragma unroll
    for (int p = 0; p < NP; ++p) {
        float px = pp[p*2], py = pp[p*2+1];
        float x0f = floorf(px), y0f = floorf(py);
        int x0 = (int)x0f, y0 = (int)y0f;
        float wx1 = px - x0f, wy1 = py - y0f;
        float wx0 = 1.f - wx1, wy0 = 1.f - wy1;
        float acc = 0.f;
        #pragma unroll
        for (int tap = 0; tap < 4; ++tap) {
            int xi = x0 + (tap & 1);
            int yi = y0 + (tap >> 1);
            float w = ((tap & 1) ? wx1 : wx0) * ((tap >> 1) ? wy1 : wy0);
            bool valid = (xi >= 0) & (xi < W_) & (yi >= 0) & (yi < H_);
            int xc = min(max(xi, 0), W_-1);
            int yc = min(max(yi, 0), H_-1);
            acc += (valid ? w : 0.f) * xin[(((size_t)(i*C_ + c))*H_ + yc)*W_ + xc];
        }
        featL[p*C_ + c] = acc;
    }
    __syncthreads();
    float acc[NP];
    #pragma unroll
    for (int p = 0; p < NP; ++p) acc[p] = 0.f;
    const float4* sfr = (const float4*)(sf_w + (size_t)c*C_);
    const float4* fL4 = (const float4*)featL;
    for (int c4 = 0; c4 < C_/4; ++c4) {
        float4 wv = sfr[c4];
        #pragma unroll
        for (int p = 0; p < NP; ++p) {
            float4 f = fL4[p*(C_/4) + c4];
            acc[p] += wv.x*f.x + wv.y*f.y + wv.z*f.z + wv.w*f.w;
        }
    }
    #pragma unroll
    for (int p = 0; p < NP; ++p) {
        float v = acc[p];
        acc[p] = v > 0.f ? SELU_SC*v : SELU_SC*SELU_AL*(__expf(v) - 1.0f);
    }
    __shared__ __align__(16) float gL[NP*C_];
    #pragma unroll
    for (int p = 0; p < NP; ++p) gL[p*C_ + c] = acc[p];
    __syncthreads();
    float d_acc = 0.f;
    for (int pc = 0; pc < NP*C_; ++pc)
        d_acc += gL[pc] * agg_w[(size_t)pc*C_ + c];
    dst[(size_t)bid*C_ + c] = d_acc;
}

__global__ __launch_bounds__(64) void k_norm(float* __restrict__ out) {
    int row = blockIdx.x;
    int l = threadIdx.x;
    float* r = out + (size_t)row*C_;
    float a = r[l], b = r[l+64];
    float ss = a*a + b*b;
    #pragma unroll
    for (int m = 1; m < 64; m <<= 1) ss += __shfl_xor(ss, m);
    float s = fmaxf(sqrtf(ss), 1e-12f);
    r[l] = a/s; r[l+64] = b/s;
}

extern "C" void kernel_launch(void* const* d_in, const int* in_sizes, int n_in,
                              void* d_out, int out_size, void* d_ws, size_t ws_size,
                              hipStream_t stream) {
    const float* x    = (const float*)d_in[0];
    const float* kpts = (const float*)d_in[1];
    const float* W1   = (const float*)d_in[2];
    const float* b1   = (const float*)d_in[3];
    const float* W2   = (const float*)d_in[4];
    const float* b2   = (const float*)d_in[5];
    const float* sfw  = (const float*)d_in[6];
    const float* aggw = (const float*)d_in[7];
    float* out_desc = (float*)d_out;
    float* out_off  = out_desc + (size_t)B_*NK*C_;

    char* ws = (char*)d_ws;
    float* pos = (float*)ws;                                  // fallback only
    const size_t W1F_OFF = (size_t)1 << 20;
    const size_t SFB_OFF = (size_t)2 << 20;
    const size_t AGG_OFF = (size_t)3 << 20;
    const size_t XT_OFF  = (size_t)1 << 26;                   // 64 MB
    const size_t XT_BYTES = (size_t)B_*H_*W_*C_*2;            // 64 MB
    bool useXT = ws_size >= XT_OFF + XT_BYTES;
    __hip_bfloat16* xtb  = (__hip_bfloat16*)(ws + XT_OFF);
    __hip_bfloat16* w1f  = (__hip_bfloat16*)(ws + W1F_OFF);
    __hip_bfloat16* sfb  = (__hip_bfloat16*)(ws + SFB_OFF);
    __hip_bfloat16* aggb = (__hip_bfloat16*)(ws + AGG_OFF);

    if (useXT) {
        k_transpose_prep<<<NT_BLK + NP_BLK, 256, 0, stream>>>(x, xtb, W1, sfw, aggw,
                                                              w1f, sfb, aggb);
        k_fused<<<NROWS/16, 512, 0, stream>>>(xtb, kpts, w1f, b1, W2, b2, sfb, aggb,
                                              out_off, out_desc);
    } else {
        k_offsets_f32<<<NROWS, 64, 0, stream>>>(x, kpts, W1, b1, W2, b2, out_off, pos);
        k_sample_f32<<<NROWS, 128, 0, stream>>>(x, pos, sfw, aggw, out_desc);
        k_norm<<<NROWS, 64, 0, stream>>>(out_desc);
    }
}

// Round 14
// 57.807 us; speedup vs baseline: 1.0580x; 1.0580x over previous
//
#include <hip/hip_runtime.h>
#include <hip/hip_bf16.h>
#include <math.h>

#define B_ 4
#define C_ 128
#define H_ 256
#define W_ 256
#define NK 2048
#define NP 8
#define HW_ (H_*W_)
#define MAXOFF 64.0f
#define NROWS (B_*NK)          // 8192

typedef short s16x8 __attribute__((ext_vector_type(8)));
typedef short s16x4 __attribute__((ext_vector_type(4)));
typedef float f32x4 __attribute__((ext_vector_type(4)));

#define SELU_SC 1.0507009873554805f
#define SELU_AL 1.6732632423543772f

#define N_W1F (36*64*8)     // 18432
#define N_SFB (8*4*64*8)    // 16384
#define N_AGG (8*8*4*64*8)  // 131072
#define NPREP (N_W1F + N_SFB + N_AGG)   // 165888
#define NT_BLK (B_*HW_/64)               // 4096 transpose tiles
#define NP_BLK 81
#define LSTR 136

__device__ inline float bf2f(short b) {
    union { unsigned int u; float f; } cv;
    cv.u = ((unsigned int)(unsigned short)b) << 16;
    return cv.f;
}
__device__ inline short f2bf_s(float f) {
    __hip_bfloat16 h = __float2bfloat16(f);
    return *(short*)&h;
}

// ---- K0: transpose x (B,C,H,W) fp32 -> xt (B,H,W,C) bf16  (+ fused preps) --
__global__ __launch_bounds__(256) void k_transpose_prep(const float* __restrict__ x,
        __hip_bfloat16* __restrict__ xt,
        const float* __restrict__ W1, const float* __restrict__ sf_w,
        const float* __restrict__ agg_w,
        __hip_bfloat16* __restrict__ w1f, __hip_bfloat16* __restrict__ sfb,
        __hip_bfloat16* __restrict__ aggb) {
    __shared__ __align__(16) __hip_bfloat16 lt[64*LSTR];
    int bid = blockIdx.x;
    int t = threadIdx.x;
    if (bid >= NT_BLK) {
        int base = ((bid - NT_BLK)*256 + t)*8;
        #pragma unroll
        for (int j = 0; j < 8; ++j) {
            int u0 = base + j;
            if (u0 < N_W1F) {
                int e = u0 & 7, l = (u0 >> 3) & 63, ks = u0 >> 9;
                int o = l & 15, c = (ks & 3)*32 + ((l >> 4) << 3) + e, ab = ks >> 2;
                w1f[u0] = __float2bfloat16(W1[o*1152 + c*9 + ab]);
            } else if (u0 < N_W1F + N_SFB) {
                int u = u0 - N_W1F;
                int e = u & 7, l = (u >> 3) & 63, ks = (u >> 9) & 3, jj = u >> 11;
                sfb[u] = __float2bfloat16(sf_w[(jj*16 + (l & 15))*128 + ks*32 + ((l >> 4) << 3) + e]);
            } else if (u0 < NPREP) {
                int u = u0 - N_W1F - N_SFB;
                int e = u & 7, l = (u >> 3) & 63, ks = (u >> 9) & 3, p = (u >> 11) & 7, jd = u >> 14;
                aggb[u] = __float2bfloat16(agg_w[((size_t)p*128 + ks*32 + ((l >> 4) << 3) + e)*128 + jd*16 + (l & 15)]);
            }
        }
        return;
    }
    int i = bid >> 10;
    int hw0 = (bid & 1023) * 64;
    const float* src = x + (size_t)i*C_*HW_ + hw0;
    #pragma unroll
    for (int k = 0; k < 8; ++k) {
        int f = t + k*256;
        int c = f >> 4, hq = f & 15;
        float4 v = *(const float4*)(src + (size_t)c*HW_ + hq*4);
        int hw = hq*4;
        lt[(hw+0)*LSTR + c] = __float2bfloat16(v.x);
        lt[(hw+1)*LSTR + c] = __float2bfloat16(v.y);
        lt[(hw+2)*LSTR + c] = __float2bfloat16(v.z);
        lt[(hw+3)*LSTR + c] = __float2bfloat16(v.w);
    }
    __syncthreads();
    __hip_bfloat16* dst = xt + ((size_t)i*HW_ + hw0)*C_;
    #pragma unroll
    for (int k = 0; k < 4; ++k) {
        int e = t + k*256;
        int hw = e >> 4, c0 = (e & 15)*8;
        *(s16x8*)(dst + (size_t)hw*C_ + c0) = *(const s16x8*)&lt[hw*LSTR + c0];
    }
}

// ------------- K1: fused pipeline, 512 thr / 8 waves, 16 kp/block ----------
#define FSTR 1032   // featL row stride (bf16)
#define HSTR 136
#define RSTR 132
#define SMEM_BYTES 34816   // max(featL 33024, Hl 8*4352=34816, red 33792)
__global__ __launch_bounds__(512, 4) void k_fused(
        const __hip_bfloat16* __restrict__ xtb, const float* __restrict__ kpts,
        const __hip_bfloat16* __restrict__ w1f, const float* __restrict__ b1,
        const float* __restrict__ W2, const float* __restrict__ b2,
        const __hip_bfloat16* __restrict__ sfb, const __hip_bfloat16* __restrict__ aggb,
        float* __restrict__ out_off, float* __restrict__ descs) {
    __shared__ __align__(16) char smem[SMEM_BYTES];
    __shared__ float W2s[16][16];
    __shared__ float posL[16][8][2];
    __shared__ float kwx[16], kwy[16];
    __shared__ int   kcx[16], kcy[16];

    int t = threadIdx.x;
    int blk = blockIdx.x;
    int i = blk >> 7;                  // 128 blocks per image
    int w = t >> 6, l = t & 63;
    int r16 = l & 15, q = l >> 4;
    int kp0 = blk * 16;

    if (t < 16) {
        int gk = kp0 + t;
        float kx = kpts[(size_t)gk*2], ky = kpts[(size_t)gk*2 + 1];
        float wx = (kx*0.5f + 0.5f) * (float)(W_-1);
        float wy = (ky*0.5f + 0.5f) * (float)(H_-1);
        int cx = (int)wx - 1; cx = min(max(cx, 0), W_-1-3);
        int cy = (int)wy - 1; cy = min(max(cy, 0), H_-1-3);
        kwx[t] = wx; kwy[t] = wy; kcx[t] = cx; kcy[t] = cy;
    }
    if (t < 256) W2s[t >> 4][t & 15] = W2[t];
    __syncthreads();

    // ---- Phase A: patch conv MFMA; 36 k-steps over 8 waves (5,5,5,5,4,4,4,4)
    float* Cp  = (float*)smem;            // [8][16][17] = 8704 B
    float* hLr = (float*)(smem + 8704);   // [16][17]    = 1088 B
    {
        const char* pb = (const char*)(xtb +
            ((size_t)(i*H_ + kcy[r16])*W_ + kcx[r16])*C_);
        f32x4 acc = {0.f, 0.f, 0.f, 0.f};
        int nst  = (w < 4) ? 5 : 4;
        int kbase = (w < 4) ? w*5 : 20 + (w-4)*4;
        for (int s = 0; s < nst; ++s) {
            int ks = kbase + s;
            int ab = ks >> 2;
            int a = ab/3, b = ab - (ab/3)*3;
            int off = ((a*W_ + b)*C_ + (ks & 3)*32 + q*8) * 2;
            s16x8 af = *(const s16x8*)(pb + off);
            s16x8 bf = *(const s16x8*)((const short*)w1f + ((size_t)ks*64 + l)*8);
            acc = __builtin_amdgcn_mfma_f32_16x16x32_bf16(af, bf, acc, 0, 0, 0);
        }
        #pragma unroll
        for (int r = 0; r < 4; ++r)
            Cp[(w*16 + q*4 + r)*17 + r16] = acc[r];
    }
    __syncthreads();
    // ---- MLP + pos (threads 0..255) ----
    if (t < 256) {
        int kp = t >> 4, o = t & 15;
        float sum = 0.f;
        #pragma unroll
        for (int ww = 0; ww < 8; ++ww)
            sum += Cp[(ww*16 + kp)*17 + o];
        hLr[kp*17 + o] = fmaxf(sum + b1[o], 0.f);
    }
    __syncthreads();
    if (t < 256) {
        int kp = t >> 4, o = t & 15;
        float acc2 = b2[o];
        #pragma unroll
        for (int oo = 0; oo < 16; ++oo)
            acc2 += hLr[kp*17 + oo] * W2s[o][oo];
        acc2 = fminf(fmaxf(acc2, -MAXOFF), MAXOFF);
        int d = o >> 3, p = o & 7;
        int gk = kp0 + kp;
        out_off[((size_t)gk*NP + p)*2 + d] = acc2;
        posL[kp][p][d] = (d ? kwy[kp] : kwx[kp]) + acc2;
    }
    __syncthreads();   // Cp/hLr dead; smem becomes featL

    // ---- Phase B: bilinear gather -> featL; 16 B loads, 4 serial iters -----
    __hip_bfloat16* featL = (__hip_bfloat16*)smem;
    {
        int grp = t >> 4, lane16 = t & 15;   // 32 groups x 16 lanes
        int c0 = lane16 * 8;
        #pragma unroll
        for (int s = 0; s < 4; ++s) {
            int pr = s*32 + grp;             // 0..127 slots (kp,p)
            int kp = pr >> 3, p = pr & 7;
            float px = posL[kp][p][0], py = posL[kp][p][1];
            float x0f = floorf(px), y0f = floorf(py);
            int x0 = (int)x0f, y0 = (int)y0f;
            float wx1 = px - x0f, wy1 = py - y0f;
            float wx0 = 1.f - wx1, wy0 = 1.f - wy1;
            float a0=0.f,a1=0.f,a2=0.f,a3=0.f,a4=0.f,a5=0.f,a6=0.f,a7=0.f;
            #pragma unroll
            for (int tap = 0; tap < 4; ++tap) {
                int xi = x0 + (tap & 1);
                int yi = y0 + (tap >> 1);
                float wgt = ((tap & 1) ? wx1 : wx0) * ((tap >> 1) ? wy1 : wy0);
                bool valid = (xi >= 0) & (xi < W_) & (yi >= 0) & (yi < H_);
                int xc = min(max(xi, 0), W_-1);
                int yc = min(max(yi, 0), H_-1);
                float wv = valid ? wgt : 0.f;
                const __hip_bfloat16* src = xtb + ((size_t)(i*H_ + yc)*W_ + xc)*C_ + c0;
                s16x8 v = *(const s16x8*)src;
                a0 += wv * bf2f(v[0]);
                a1 += wv * bf2f(v[1]);
                a2 += wv * bf2f(v[2]);
                a3 += wv * bf2f(v[3]);
                a4 += wv * bf2f(v[4]);
                a5 += wv * bf2f(v[5]);
                a6 += wv * bf2f(v[6]);
                a7 += wv * bf2f(v[7]);
            }
            s16x8 ov;
            ov[0] = f2bf_s(a0); ov[1] = f2bf_s(a1);
            ov[2] = f2bf_s(a2); ov[3] = f2bf_s(a3);
            ov[4] = f2bf_s(a4); ov[5] = f2bf_s(a5);
            ov[6] = f2bf_s(a6); ov[7] = f2bf_s(a7);
            *(s16x8*)(featL + kp*FSTR + p*C_ + c0) = ov;
        }
    }
    __syncthreads();

    // ---- Phase C: wave w owns position p = w ----
    int p = w;
    s16x8 af[4];
    #pragma unroll
    for (int ks = 0; ks < 4; ++ks)
        af[ks] = *(const s16x8*)(featL + r16*FSTR + p*C_ + ks*32 + q*8);
    __syncthreads();   // featL dead; smem becomes Hl (per-wave 4352 B x 8)

    __hip_bfloat16* Hl = (__hip_bfloat16*)(smem + (size_t)w*4352);  // [16][HSTR]
    f32x4 dacc[8];
    #pragma unroll
    for (int jd = 0; jd < 8; ++jd) dacc[jd] = (f32x4){0.f,0.f,0.f,0.f};
    #pragma unroll
    for (int j = 0; j < 8; ++j) {
        f32x4 acc = (f32x4){0.f,0.f,0.f,0.f};
        const short* sb = (const short*)sfb + ((j*4)*64 + l)*8;
        #pragma unroll
        for (int ks = 0; ks < 4; ++ks)
            acc = __builtin_amdgcn_mfma_f32_16x16x32_bf16(af[ks], *(const s16x8*)(sb + ks*512), acc, 0, 0, 0);
        #pragma unroll
        for (int r = 0; r < 4; ++r) {
            float v = acc[r];
            v = v > 0.f ? SELU_SC*v : SELU_SC*SELU_AL*(__expf(v) - 1.0f);
            Hl[(q*4 + r)*HSTR + j*16 + r16] = __float2bfloat16(v);
        }
    }
    s16x8 ah[4];
    #pragma unroll
    for (int ks = 0; ks < 4; ++ks)
        ah[ks] = *(const s16x8*)(Hl + r16*HSTR + ks*32 + q*8);
    #pragma unroll
    for (int jd = 0; jd < 8; ++jd) {
        const short* ab = (const short*)aggb + (((jd*8 + p)*4)*64 + l)*8;
        #pragma unroll
        for (int ks = 0; ks < 4; ++ks)
            dacc[jd] = __builtin_amdgcn_mfma_f32_16x16x32_bf16(ah[ks], *(const s16x8*)(ab + ks*512), dacc[jd], 0, 0, 0);
    }
    __syncthreads();   // all Hl reads done; smem becomes red [4][16][RSTR]

    // ---- two-round reduction over 8 waves ----
    float* red = (float*)smem;
    if (w < 4) {
        #pragma unroll
        for (int jd = 0; jd < 8; ++jd)
            #pragma unroll
            for (int r = 0; r < 4; ++r)
                red[((size_t)w*16 + q*4 + r)*RSTR + jd*16 + r16] = dacc[jd][r];
    }
    __syncthreads();
    if (w >= 4) {
        #pragma unroll
        for (int jd = 0; jd < 8; ++jd)
            #pragma unroll
            for (int r = 0; r < 4; ++r) {
                size_t idx = ((size_t)(w-4)*16 + q*4 + r)*RSTR + jd*16 + r16;
                red[idx] += dacc[jd][r];
            }
    }
    __syncthreads();

    // ---- fused L2-normalize + store (16 rows x 128 cols over 512 thr) ----
    {
        int row = t >> 5, c5 = t & 31;
        float v[4];
        float ss = 0.f;
        #pragma unroll
        for (int k = 0; k < 4; ++k) {
            int col = c5 + 32*k;
            float s = red[(0*16 + row)*RSTR + col] + red[(1*16 + row)*RSTR + col]
                    + red[(2*16 + row)*RSTR + col] + red[(3*16 + row)*RSTR + col];
            v[k] = s; ss += s*s;
        }
        ss += __shfl_xor(ss, 1);
        ss += __shfl_xor(ss, 2);
        ss += __shfl_xor(ss, 4);
        ss += __shfl_xor(ss, 8);
        ss += __shfl_xor(ss, 16);
        float sc = fmaxf(sqrtf(ss), 1e-12f);
        #pragma unroll
        for (int k = 0; k < 4; ++k)
            descs[(size_t)(kp0 + row)*C_ + c5 + 32*k] = v[k] / sc;
    }
}

// ---------------- fallback path (no workspace): fp32 direct -----------------
__global__ __launch_bounds__(64) void k_offsets_f32(const float* __restrict__ xin,
        const float* __restrict__ kpts, const float* __restrict__ W1,
        const float* __restrict__ b1, const float* __restrict__ W2,
        const float* __restrict__ b2, float* __restrict__ out_off,
        float* __restrict__ pos) {
    __shared__ float pL[1152];
    __shared__ float hL2[16];
    __shared__ float oL[16];
    int bid = blockIdx.x;
    int i = bid >> 11;
    int t = threadIdx.x;
    float kx = kpts[(size_t)bid*2 + 0];
    float ky = kpts[(size_t)bid*2 + 1];
    float kwhx = (kx*0.5f + 0.5f) * (float)(W_-1);
    float kwhy = (ky*0.5f + 0.5f) * (float)(H_-1);
    int cx = (int)kwhx - 1; cx = cx < 0 ? 0 : (cx > 252 ? 252 : cx);
    int cy = (int)kwhy - 1; cy = cy < 0 ? 0 : (cy > 252 ? 252 : cy);
    for (int e = t; e < 1152; e += 64) {
        int a = e/384; int r = e - a*384; int b = r >> 7; int c = r & 127;
        pL[e] = xin[(((size_t)(i*C_ + c))*H_ + cy + a)*W_ + cx + b];
    }
    __syncthreads();
    int o = t & 15;
    int chunk = t >> 4;
    float partial = 0.f;
    const float* w1r = W1 + o*1152;
    for (int c = chunk*32; c < chunk*32 + 32; ++c) {
        #pragma unroll
        for (int ab = 0; ab < 9; ++ab) {
            const int a = ab/3, b = ab - (ab/3)*3;
            partial += w1r[c*9 + ab] * pL[a*384 + b*128 + c];
        }
    }
    partial += __shfl_xor(partial, 16);
    partial += __shfl_xor(partial, 32);
    float h1 = fmaxf(partial + b1[o], 0.f);
    if (t < 16) hL2[t] = h1;
    __syncthreads();
    if (t < 16) {
        float acc = b2[t];
        const float* w2r = W2 + t*16;
        #pragma unroll
        for (int oo = 0; oo < 16; ++oo) acc += w2r[oo]*hL2[oo];
        acc = fminf(fmaxf(acc, -MAXOFF), MAXOFF);
        oL[t] = acc;
    }
    __syncthreads();
    if (t < 8) {
        float ox = oL[t], oy = oL[8 + t];
        size_t base = ((size_t)bid*NP + t)*2;
        out_off[base]   = ox;
        out_off[base+1] = oy;
        pos[base]   = kwhx + ox;
        pos[base+1] = kwhy + oy;
    }
}

__global__ __launch_bounds__(128) void k_sample_f32(const float* __restrict__ xin,
        const float* __restrict__ pos, const float* __restrict__ sf_w,
        const float* __restrict__ agg_w, float* __restrict__ dst) {
    __shared__ __align__(16) float featL[NP*C_];
    __shared__ float pp[16];
    int bid = blockIdx.x;
    int i = bid >> 11;
    int c = threadIdx.x;
    if (c < 16) pp[c] = pos[(size_t)bid*16 + c];
    __syncthreads();
    #pragma unroll
    for (int p = 0; p < NP; ++p) {
        float px = pp[p*2], py = pp[p*2+1];
        float x0f = floorf(px), y0f = floorf(py);
        int x0 = (int)x0f, y0 = (int)y0f;
        float wx1 = px - x0f, wy1 = py - y0f;
        float wx0 = 1.f - wx1, wy0 = 1.f - wy1;
        float acc = 0.f;
        #pragma unroll
        for (int tap = 0; tap < 4; ++tap) {
            int xi = x0 + (tap & 1);
            int yi = y0 + (tap >> 1);
            float w = ((tap & 1) ? wx1 : wx0) * ((tap >> 1) ? wy1 : wy0);
            bool valid = (xi >= 0) & (xi < W_) & (yi >= 0) & (yi < H_);
            int xc = min(max(xi, 0), W_-1);
            int yc = min(max(yi, 0), H_-1);
            acc += (valid ? w : 0.f) * xin[(((size_t)(i*C_ + c))*H_ + yc)*W_ + xc];
        }
        featL[p*C_ + c] = acc;
    }
    __syncthreads();
    float acc[NP];
    #pragma unroll
    for (int p = 0; p < NP; ++p) acc[p] = 0.f;
    const float4* sfr = (const float4*)(sf_w + (size_t)c*C_);
    const float4* fL4 = (const float4*)featL;
    for (int c4 = 0; c4 < C_/4; ++c4) {
        float4 wv = sfr[c4];
        #pragma unroll
        for (int p = 0; p < NP; ++p) {
            float4 f = fL4[p*(C_/4) + c4];
            acc[p] += wv.x*f.x + wv.y*f.y + wv.z*f.z + wv.w*f.w;
        }
    }
    #pragma unroll
    for (int p = 0; p < NP; ++p) {
        float v = acc[p];
        acc[p] = v > 0.f ? SELU_SC*v : SELU_SC*SELU_AL*(__expf(v) - 1.0f);
    }
    __shared__ __align__(16) float gL[NP*C_];
    #pragma unroll
    for (int p = 0; p < NP; ++p) gL[p*C_ + c] = acc[p];
    __syncthreads();
    float d_acc = 0.f;
    for (int pc = 0; pc < NP*C_; ++pc)
        d_acc += gL[pc] * agg_w[(size_t)pc*C_ + c];
    dst[(size_t)bid*C_ + c] = d_acc;
}

__global__ __launch_bounds__(64) void k_norm(float* __restrict__ out) {
    int row = blockIdx.x;
    int l = threadIdx.x;
    float* r = out + (size_t)row*C_;
    float a = r[l], b = r[l+64];
    float ss = a*a + b*b;
    #pragma unroll
    for (int m = 1; m < 64; m <<= 1) ss += __shfl_xor(ss, m);
    float s = fmaxf(sqrtf(ss), 1e-12f);
    r[l] = a/s; r[l+64] = b/s;
}

extern "C" void kernel_launch(void* const* d_in, const int* in_sizes, int n_in,
                              void* d_out, int out_size, void* d_ws, size_t ws_size,
                              hipStream_t stream) {
    const float* x    = (const float*)d_in[0];
    const float* kpts = (const float*)d_in[1];
    const float* W1   = (const float*)d_in[2];
    const float* b1   = (const float*)d_in[3];
    const float* W2   = (const float*)d_in[4];
    const float* b2   = (const float*)d_in[5];
    const float* sfw  = (const float*)d_in[6];
    const float* aggw = (const float*)d_in[7];
    float* out_desc = (float*)d_out;
    float* out_off  = out_desc + (size_t)B_*NK*C_;

    char* ws = (char*)d_ws;
    float* pos = (float*)ws;                                  // fallback only
    const size_t W1F_OFF = (size_t)1 << 20;
    const size_t SFB_OFF = (size_t)2 << 20;
    const size_t AGG_OFF = (size_t)3 << 20;
    const size_t XT_OFF  = (size_t)1 << 26;                   // 64 MB
    const size_t XT_BYTES = (size_t)B_*H_*W_*C_*2;            // 64 MB
    bool useXT = ws_size >= XT_OFF + XT_BYTES;
    __hip_bfloat16* xtb  = (__hip_bfloat16*)(ws + XT_OFF);
    __hip_bfloat16* w1f  = (__hip_bfloat16*)(ws + W1F_OFF);
    __hip_bfloat16* sfb  = (__hip_bfloat16*)(ws + SFB_OFF);
    __hip_bfloat16* aggb = (__hip_bfloat16*)(ws + AGG_OFF);

    if (useXT) {
        k_transpose_prep<<<NT_BLK + NP_BLK, 256, 0, stream>>>(x, xtb, W1, sfw, aggw,
                                                              w1f, sfb, aggb);
        k_fused<<<NROWS/16, 512, 0, stream>>>(xtb, kpts, w1f, b1, W2, b2, sfb, aggb,
                                              out_off, out_desc);
    } else {
        k_offsets_f32<<<NROWS, 64, 0, stream>>>(x, kpts, W1, b1, W2, b2, out_off, pos);
        k_sample_f32<<<NROWS, 128, 0, stream>>>(x, pos, sfw, aggw, out_desc);
        k_norm<<<NROWS, 64, 0, stream>>>(out_desc);
    }
}